// Round 2
// baseline (176.644 us; speedup 1.0000x reference)
//
#include <hip/hip_runtime.h>
#include <hip/hip_bf16.h>

// Stratified max pooling: out[b,c] = max over j with labels[j]==c of values[b,j]
// values: [B, N] fp32, labels: [N] int32 (harness converts), out: [B, C] fp32.
//
// Round 2: no global atomics. K1 (strat_part) computes per-(column-split,
// row-group) partial maxima in LDS (monotone-encoded u32, ds atomicMax) and
// flushes them to d_ws with plain stores: part[split][b][c]. K2 (strat_reduce)
// max-reduces over splits and decodes into d_out. Round-1 atomic path kept as
// fallback if d_ws is too small / shapes are awkward.

#define TPB   256
#define ROWS  8       // rows per block
#define CACC  128     // LDS accumulator stride (requires C <= 128 on main path)

#define ENC_NEG_INF 0x007FFFFFu   // enc(-inf)

__device__ __forceinline__ unsigned enc(float f) {
    unsigned u = __float_as_uint(f);
    return (u & 0x80000000u) ? ~u : (u | 0x80000000u);
}
__device__ __forceinline__ float dec(unsigned u) {
    unsigned b = (u & 0x80000000u) ? (u & 0x7FFFFFFFu) : ~u;
    return __uint_as_float(b);
}

// ---------------- main path: partials + reduce (no global atomics) ----------

// Grid: (S splits, B/ROWS row-groups). Block bx strides over 1024-col tiles
// t = bx, bx+S, ... < T. Partials: part[bx][b][c], plain stores.
__global__ __launch_bounds__(TPB) void strat_part(
    const float* __restrict__ values, const int* __restrict__ labels,
    unsigned* __restrict__ part, int B, int N, int C, int S, int T) {
    __shared__ unsigned acc[ROWS * CACC];

    const int tid  = threadIdx.x;
    const int bx   = blockIdx.x;
    const int row0 = blockIdx.y * ROWS;
    const int rmax = min(ROWS, B - row0);

    for (int i = tid; i < ROWS * CACC; i += TPB) acc[i] = ENC_NEG_INF;
    __syncthreads();

    for (int t = bx; t < T; t += S) {
        const int base = t * 1024 + tid * 4;
        if (t * 1024 + 1024 <= N) {
            const int4 L = *(const int4*)(labels + base);
            if (rmax == ROWS) {
                float4 v[ROWS];
#pragma unroll
                for (int r = 0; r < ROWS; ++r)
                    v[r] = *(const float4*)(values + (size_t)(row0 + r) * N + base);
#pragma unroll
                for (int r = 0; r < ROWS; ++r) {
                    unsigned* a = acc + r * CACC;
                    atomicMax(&a[L.x], enc(v[r].x));
                    atomicMax(&a[L.y], enc(v[r].y));
                    atomicMax(&a[L.z], enc(v[r].z));
                    atomicMax(&a[L.w], enc(v[r].w));
                }
            } else {
                for (int r = 0; r < rmax; ++r) {
                    float4 v = *(const float4*)(values + (size_t)(row0 + r) * N + base);
                    unsigned* a = acc + r * CACC;
                    atomicMax(&a[L.x], enc(v.x));
                    atomicMax(&a[L.y], enc(v.y));
                    atomicMax(&a[L.z], enc(v.z));
                    atomicMax(&a[L.w], enc(v.w));
                }
            }
        } else {
            // tail tile: scalar, guarded (at most one tile of T)
#pragma unroll
            for (int e = 0; e < 4; ++e) {
                const int j = base + e;
                if (j < N) {
                    const int c = labels[j];
                    for (int r = 0; r < rmax; ++r)
                        atomicMax(&acc[r * CACC + c],
                                  enc(values[(size_t)(row0 + r) * N + j]));
                }
            }
        }
    }

    __syncthreads();

    // Plain-store flush of this block's partial slice (contiguous 800 words).
    unsigned* dst = part + (size_t)bx * B * C;
    for (int i = tid; i < rmax * C; i += TPB) {
        const int r = i / C, c = i - r * C;
        dst[(size_t)(row0 + r) * C + c] = acc[r * CACC + c];
    }
}

// K2: out[i] = dec(max over s of part[s][i]), i in [0, B*C)
__global__ __launch_bounds__(TPB) void strat_reduce(
    const unsigned* __restrict__ part, float* __restrict__ out, int BC, int S) {
    const int i = blockIdx.x * TPB + threadIdx.x;
    if (i >= BC) return;
    unsigned m = ENC_NEG_INF;
    for (int s = 0; s < S; ++s) m = max(m, part[(size_t)s * BC + i]);
    out[i] = dec(m);
}

// ---------------- fallback path (round-1): global atomics into d_out --------

#define FCPAD 257

__global__ __launch_bounds__(TPB) void strat_init(unsigned* __restrict__ out_enc, int n) {
    int i = blockIdx.x * TPB + threadIdx.x;
    if (i < n) out_enc[i] = ENC_NEG_INF;
}

__global__ __launch_bounds__(TPB) void strat_main_atomic(
    const float* __restrict__ values, const int* __restrict__ labels,
    unsigned* __restrict__ out_enc, int B, int N, int C, int T) {
    __shared__ unsigned acc[ROWS * FCPAD];
    const int tid  = threadIdx.x;
    const int row0 = blockIdx.y * ROWS;
    const int rmax = min(ROWS, B - row0);

    for (int i = tid; i < ROWS * FCPAD; i += TPB) acc[i] = ENC_NEG_INF;
    __syncthreads();

    const int t = blockIdx.x;
#pragma unroll
    for (int e = 0; e < 4; ++e) {
        const int j = t * 1024 + tid * 4 + e;
        if (j < N) {
            const int c = labels[j];
            for (int r = 0; r < rmax; ++r)
                atomicMax(&acc[r * FCPAD + c],
                          enc(values[(size_t)(row0 + r) * N + j]));
        }
    }
    __syncthreads();
    for (int i = tid; i < rmax * C; i += TPB) {
        const int r = i / C, c = i - r * C;
        atomicMax(&out_enc[(size_t)(row0 + r) * C + c], acc[r * FCPAD + c]);
    }
}

__global__ __launch_bounds__(TPB) void strat_decode(unsigned* __restrict__ buf, int n) {
    int i = blockIdx.x * TPB + threadIdx.x;
    if (i < n) {
        float f = dec(buf[i]);
        ((float*)buf)[i] = f;
    }
}

// ---------------------------------------------------------------------------

extern "C" void kernel_launch(void* const* d_in, const int* in_sizes, int n_in,
                              void* d_out, int out_size, void* d_ws, size_t ws_size,
                              hipStream_t stream) {
    const float* values = (const float*)d_in[0];
    const int*   labels = (const int*)d_in[1];
    const int N  = in_sizes[1];
    const int B  = in_sizes[0] / N;
    const int C  = out_size / B;
    const int BC = B * C;
    const int T  = (N + 1023) / 1024;   // 1024-col tiles
    const int RG = (B + ROWS - 1) / ROWS;

    // Choose split count S so partials fit in d_ws; 98 balances 196 tiles.
    int S = 98;
    const size_t per_split = (size_t)BC * sizeof(unsigned);
    if (per_split > 0 && (size_t)S * per_split > ws_size)
        S = (int)(ws_size / per_split);
    if (S > T) S = T;

    const bool main_ok = (S >= 1) && (C <= CACC) && (N % 4 == 0);

    if (main_ok) {
        unsigned* part = (unsigned*)d_ws;
        dim3 grid(S, RG);
        strat_part<<<grid, TPB, 0, stream>>>(values, labels, part, B, N, C, S, T);
        strat_reduce<<<(BC + TPB - 1) / TPB, TPB, 0, stream>>>(
            part, (float*)d_out, BC, S);
    } else {
        // fallback: atomic flush into d_out (round-1 structure), C <= 256
        unsigned* out_enc = (unsigned*)d_out;
        const int init_blocks = (out_size + TPB - 1) / TPB;
        strat_init<<<init_blocks, TPB, 0, stream>>>(out_enc, out_size);
        dim3 grid(T, RG);
        strat_main_atomic<<<grid, TPB, 0, stream>>>(values, labels, out_enc, B, N, C, T);
        strat_decode<<<init_blocks, TPB, 0, stream>>>(out_enc, out_size);
    }
}